// Round 5
// baseline (612.257 us; speedup 1.0000x reference)
//
#include <hip/hip_runtime.h>

// Attention_884763263569 on gfx950 — v7 = v6 + DIAGNOSTIC double-launch of attn_fused.
// attn_fused is idempotent (pure function of x, Wf, bfc -> out), so launching it twice is
// correctness-neutral; dur_us(v7) - dur_us(v6) = the true duration of one attn_fused
// dispatch, which is invisible in the top-5 rocprof table (all five slots are the harness's
// 246 us / 1.6 GB workspace poison fills). This settles whether attn is ~100 us (near the
// 64 us x-read floor -> near-roofline) or ~240 us (large headroom remains).
// Kernels below are BYTE-IDENTICAL to v6 (524.06 us, passed, absmax 0.015625).

typedef __attribute__((ext_vector_type(4))) float  f32x4;
typedef __attribute__((ext_vector_type(8))) _Float16 h16x8;

#define T_VIEWS 3
#define D_DIM   512
#define P_DIM   32
#define C_DIM   10
#define NROWS   80          // padded logical rows per t
#define NT      5           // n-tiles of 16
#define KC      16          // k-chunks of 32 per t
#define NSTEPS  48          // T_VIEWS*KC
#define JPER    4           // k-steps per super-chunk
#define NSUPER  (NSTEPS/JPER)            // 12
#define STEP_B  (NT*1024)                // 5120 B of fragments per k-step
#define CHUNK_B (JPER*STEP_B)            // 20480 B per super-chunk
#define WAVES_PER_BLOCK 4
#define SAMPLES_PER_BLOCK (16 * WAVES_PER_BLOCK)   // 64

// ---------------- Kernel A: build fragment-ordered fp16 weights in d_ws ----------------
// Logical (t, j, d) -> frag addr (((t*KC+kc)*NT+n)*64 + quad*16+col)*8 + jj
// K-permutation within a 32-chunk: r = d&31 -> quad=(r>>2)&3, jj=((r>>4)<<2)|(r&3),
// i.e. element jj of quad q is k = (jj<4 ? 4q+jj : 16+4q+jj-4). Matches the A-side loads.
__global__ void build_weights(const float* __restrict__ Wk,
                              const float* __restrict__ Wv,
                              const float* __restrict__ Wq,
                              const float* __restrict__ Wfc,
                              _Float16* __restrict__ Wf) {
    const int row = blockIdx.x;          // 0 .. 3*80-1
    const int t   = row / NROWS;
    const int j   = row % NROWS;
    const int d   = threadIdx.x;         // 0..511
    float val;
    if (j < 32) {
        val = Wk[j * D_DIM + d];
    } else if (j < 64) {
        const int p = j - 32;
        val = Wq[p * (T_VIEWS * D_DIM) + t * D_DIM + d];
    } else if (j < 64 + C_DIM) {
        const int i = j - 64;
        float s = 0.f;
        #pragma unroll
        for (int p = 0; p < P_DIM; ++p)
            s += Wfc[i * P_DIM + p] * Wv[p * D_DIM + d];
        val = s;
    } else {
        val = 0.f;                        // pad rows (d_ws is poisoned -> must zero)
    }
    const int n = j >> 4, coln = j & 15;
    const int kc = d >> 5, r = d & 31;
    const int quad = (r >> 2) & 3;                 // K-permuted quad
    const int jj   = ((r >> 4) << 2) | (r & 3);    // K-permuted element index
    const size_t addr = (size_t)((((t * KC + kc) * NT + n) * 64) + quad * 16 + coln) * 8 + jj;
    Wf[addr] = (_Float16)val;
}

// ---------------- Main fused kernel ----------------
__global__ __launch_bounds__(256, 3) void attn_fused(
        const float* __restrict__ x,
        const _Float16* __restrict__ Wf,
        const float* __restrict__ bfc,
        float* __restrict__ out) {
    __shared__ char lds[2 * CHUNK_B];    // 40 KB double-buffered Wf fragment store

    const int lane = threadIdx.x & 63;
    const int wave = threadIdx.x >> 6;
    const int col  = lane & 15;          // MFMA: A-row m (sample) / B-col n / C-col
    const int quad = lane >> 4;          // MFMA: k-group / C row-group
    const int row_base = blockIdx.x * SAMPLES_PER_BLOCK + wave * 16;

    // accumulators: k per-t (2 halves), q SHARED across t (MFMA C-chain), yv per-t
    f32x4 acc_k[3][2];
    f32x4 acc_q[2];
    f32x4 acc_y[3];
    #pragma unroll
    for (int t = 0; t < 3; ++t) {
        acc_k[t][0] = (f32x4)0.f;
        acc_k[t][1] = (f32x4)0.f;
        acc_y[t]    = (f32x4)0.f;
    }
    acc_q[0] = (f32x4)0.f;
    acc_q[1] = (f32x4)0.f;

    // A-operand: lane (col,quad) -> sample row = col; K-permuted:
    //   x0 @ +quad*4 floats (k = 4q..4q+3), x1 @ +64B further (k = 16+4q..16+4q+3).
    // Each x-load instruction covers 16 full 64B lines, each line touched exactly once.
    const float* xbase = x + (size_t)(row_base + col) * (T_VIEWS * D_DIM) + quad * 4;
    const char*  wfg   = (const char*)Wf + lane * 16;   // per-lane global src for Wf staging

    f32x4 xA[2 * JPER];   // x regs, even chunks
    f32x4 xB[2 * JPER];   // x regs, odd chunks

    // stage Wf chunk u into lds[u&1] (4 waves x 5 glds of 1KB)
    auto GLDS = [&](int u) {
        #pragma unroll
        for (int i = 0; i < 5; ++i) {
            const int idx = wave * 5 + i;
            __builtin_amdgcn_global_load_lds(
                (const __attribute__((address_space(1))) void*)(wfg + (size_t)u * CHUNK_B + idx * 1024),
                (__attribute__((address_space(3))) void*)(lds + (u & 1) * CHUNK_B + idx * 1024),
                16, 0, 0);
        }
    };
    // issue the 8 x-loads of chunk u into xr (u compile-time after unroll)
    auto LOADX = [&](int u, f32x4* xr) {
        #pragma unroll
        for (int j = 0; j < JPER; ++j) {
            const int s = u * JPER + j, t = s >> 4, kc = s & 15;
            const float* xp = xbase + t * D_DIM + kc * 32;
            xr[2 * j]     = __builtin_nontemporal_load((const f32x4*)xp);
            xr[2 * j + 1] = __builtin_nontemporal_load((const f32x4*)(xp + 16));
        }
    };
    // compute chunk u from lds[u&1] + xr
    auto BODY = [&](int u, const f32x4* xr) {
        const char* buf = lds + (u & 1) * CHUNK_B;
        #pragma unroll
        for (int j = 0; j < JPER; ++j) {
            const int s = u * JPER + j, t = s >> 4;   // compile-time post-unroll
            h16x8 b[NT];
            #pragma unroll
            for (int n = 0; n < NT; ++n)
                b[n] = *(const h16x8*)(buf + j * STEP_B + n * 1024 + lane * 16);
            h16x8 a;
            #pragma unroll
            for (int i = 0; i < 4; ++i) {
                a[i]     = (_Float16)xr[2 * j][i];
                a[i + 4] = (_Float16)xr[2 * j + 1][i];
            }
            acc_k[t][0] = __builtin_amdgcn_mfma_f32_16x16x32_f16(a, b[0], acc_k[t][0], 0, 0, 0);
            acc_k[t][1] = __builtin_amdgcn_mfma_f32_16x16x32_f16(a, b[1], acc_k[t][1], 0, 0, 0);
            acc_q[0]    = __builtin_amdgcn_mfma_f32_16x16x32_f16(a, b[2], acc_q[0],    0, 0, 0);
            acc_q[1]    = __builtin_amdgcn_mfma_f32_16x16x32_f16(a, b[3], acc_q[1],    0, 0, 0);
            acc_y[t]    = __builtin_amdgcn_mfma_f32_16x16x32_f16(a, b[4], acc_y[t],    0, 0, 0);
        }
    };

    // ---- prologue: glds(0) + x(0) + x(1) in flight; retire only glds(0) (vmcnt 16 = x0+x1) ----
    GLDS(0);
    LOADX(0, xA);
    LOADX(1, xB);
    asm volatile("s_waitcnt vmcnt(16)" ::: "memory");
    __builtin_amdgcn_sched_barrier(0);
    __builtin_amdgcn_s_barrier();

    // ---- main loop, fully unrolled: counted vmcnt keeps x(u+2) in flight across barriers ----
    #pragma unroll
    for (int u = 0; u < NSUPER; ++u) {
        f32x4* xcur = (u & 1) ? xB : xA;
        if (u + 1 < NSUPER) GLDS(u + 1);          // into lds[(u+1)&1]
        BODY(u, xcur);                            // consume x(u); compiler auto-waits counted
        if (u + 2 < NSUPER) LOADX(u + 2, xcur);   // overwrite AFTER consumption (same parity)
        if (u + 1 < NSUPER) {
            if (u + 2 < NSUPER) {
                // queue (oldest->newest): x(u+1):8, glds(u+1):5, x(u+2):8 -> retire first 13
                asm volatile("s_waitcnt vmcnt(8)" ::: "memory");
            } else {
                // tail (u = NSUPER-2): nothing issued after glds(u+1) -> full drain is cheap
                asm volatile("s_waitcnt vmcnt(0)" ::: "memory");
            }
            __builtin_amdgcn_sched_barrier(0);
            __builtin_amdgcn_s_barrier();
        }
    }

    // ---------------- Epilogue (registers + shfl only) ----------------
    // C layout: element r holds sample row (quad*4 + r), column (n*16 + col).
    const float bias = (col < C_DIM) ? bfc[col] : 0.f;

    float outv[4];
    #pragma unroll
    for (int r = 0; r < 4; ++r) {
        const float qa = acc_q[0][r];     // q[sample][p=col]
        const float qb = acc_q[1][r];     // q[sample][p=16+col]
        float s0 = qa * acc_k[0][0][r] + qb * acc_k[0][1][r];
        float s1 = qa * acc_k[1][0][r] + qb * acc_k[1][1][r];
        float s2 = qa * acc_k[2][0][r] + qb * acc_k[2][1][r];
        #pragma unroll
        for (int msk = 1; msk <= 8; msk <<= 1) {
            s0 += __shfl_xor(s0, msk, 64);
            s1 += __shfl_xor(s1, msk, 64);
            s2 += __shfl_xor(s2, msk, 64);
        }
        const float mx = fmaxf(s0, fmaxf(s1, s2));
        const float e0 = __expf(s0 - mx);
        const float e1 = __expf(s1 - mx);
        const float e2 = __expf(s2 - mx);
        const float inv = 1.f / (e0 + e1 + e2);
        outv[r] = (e0 * acc_y[0][r] + e1 * acc_y[1][r] + e2 * acc_y[2][r]) * inv + bias;
    }
    if (col < C_DIM) {
        const int b0 = row_base + quad * 4;
        #pragma unroll
        for (int r = 0; r < 4; ++r)
            out[(size_t)(b0 + r) * C_DIM + col] = outv[r];
    }
}

extern "C" void kernel_launch(void* const* d_in, const int* in_sizes, int n_in,
                              void* d_out, int out_size, void* d_ws, size_t ws_size,
                              hipStream_t stream) {
    const float* x   = (const float*)d_in[0];
    const float* Wk  = (const float*)d_in[1];
    const float* Wv  = (const float*)d_in[2];
    const float* Wq  = (const float*)d_in[3];
    const float* Wfc = (const float*)d_in[4];
    const float* bfc = (const float*)d_in[5];
    _Float16* Wf = (_Float16*)d_ws;       // 3*80*512 halfs = 240 KB, fragment-ordered

    hipLaunchKernelGGL(build_weights, dim3(T_VIEWS * NROWS), dim3(D_DIM), 0, stream,
                       Wk, Wv, Wq, Wfc, Wf);

    const int B_TOTAL = in_sizes[0] / (T_VIEWS * D_DIM);      // 65536
    const int blocks = B_TOTAL / SAMPLES_PER_BLOCK;           // 1024

    // DIAGNOSTIC double-launch: attn_fused is idempotent; the dur_us delta vs v6
    // equals one attn_fused dispatch duration (invisible in top-5 otherwise).
    hipLaunchKernelGGL(attn_fused, dim3(blocks), dim3(256), 0, stream,
                       x, Wf, bfc, (float*)d_out);
    hipLaunchKernelGGL(attn_fused, dim3(blocks), dim3(256), 0, stream,
                       x, Wf, bfc, (float*)d_out);
}

// Round 6
// 533.714 us; speedup vs baseline: 1.1472x; 1.1472x over previous
//
#include <hip/hip_runtime.h>

// Attention_884763263569 on gfx950 — v8 = v6 with PLAIN x loads (drop nontemporal).
// x:[65536,3,512] f32, Wk/Wv:[32,512], Wq:[32,1536], Wfc:[10,32], bfc:[10] -> out [65536,10] f32.
//
// v7 diagnostic (double-launch): attn_fused = 88.2 us vs the 64.4 us BW floor (403 MB x @ 6.3 TB/s)
// => 73% of achievable read BW; harness-fixed ~436 us. Single-variable A/B this round: the
// __builtin_nontemporal_load on the x stream (inherited from v2, never isolated) may fragment
// L2 sectoring/coalescing of the 16-rows-x-64B per-instruction pattern; every >80%-of-peak
// reference stream in this session (harness fills, copy ubench) uses plain accesses.
// Everything else byte-identical to v6 (524.06 us best): full unroll, counted-vmcnt pipeline,
// 2-chunk x reg prefetch, Wf LDS dbuf, K-permuted full-line loads, register epilogue.

typedef __attribute__((ext_vector_type(4))) float  f32x4;
typedef __attribute__((ext_vector_type(8))) _Float16 h16x8;

#define T_VIEWS 3
#define D_DIM   512
#define P_DIM   32
#define C_DIM   10
#define NROWS   80          // padded logical rows per t
#define NT      5           // n-tiles of 16
#define KC      16          // k-chunks of 32 per t
#define NSTEPS  48          // T_VIEWS*KC
#define JPER    4           // k-steps per super-chunk
#define NSUPER  (NSTEPS/JPER)            // 12
#define STEP_B  (NT*1024)                // 5120 B of fragments per k-step
#define CHUNK_B (JPER*STEP_B)            // 20480 B per super-chunk
#define WAVES_PER_BLOCK 4
#define SAMPLES_PER_BLOCK (16 * WAVES_PER_BLOCK)   // 64

// ---------------- Kernel A: build fragment-ordered fp16 weights in d_ws ----------------
// Logical (t, j, d) -> frag addr (((t*KC+kc)*NT+n)*64 + quad*16+col)*8 + jj
// K-permutation within a 32-chunk: r = d&31 -> quad=(r>>2)&3, jj=((r>>4)<<2)|(r&3),
// i.e. element jj of quad q is k = (jj<4 ? 4q+jj : 16+4q+jj-4). Matches the A-side loads.
__global__ void build_weights(const float* __restrict__ Wk,
                              const float* __restrict__ Wv,
                              const float* __restrict__ Wq,
                              const float* __restrict__ Wfc,
                              _Float16* __restrict__ Wf) {
    const int row = blockIdx.x;          // 0 .. 3*80-1
    const int t   = row / NROWS;
    const int j   = row % NROWS;
    const int d   = threadIdx.x;         // 0..511
    float val;
    if (j < 32) {
        val = Wk[j * D_DIM + d];
    } else if (j < 64) {
        const int p = j - 32;
        val = Wq[p * (T_VIEWS * D_DIM) + t * D_DIM + d];
    } else if (j < 64 + C_DIM) {
        const int i = j - 64;
        float s = 0.f;
        #pragma unroll
        for (int p = 0; p < P_DIM; ++p)
            s += Wfc[i * P_DIM + p] * Wv[p * D_DIM + d];
        val = s;
    } else {
        val = 0.f;                        // pad rows (d_ws is poisoned -> must zero)
    }
    const int n = j >> 4, coln = j & 15;
    const int kc = d >> 5, r = d & 31;
    const int quad = (r >> 2) & 3;                 // K-permuted quad
    const int jj   = ((r >> 4) << 2) | (r & 3);    // K-permuted element index
    const size_t addr = (size_t)((((t * KC + kc) * NT + n) * 64) + quad * 16 + coln) * 8 + jj;
    Wf[addr] = (_Float16)val;
}

// ---------------- Main fused kernel ----------------
__global__ __launch_bounds__(256, 3) void attn_fused(
        const float* __restrict__ x,
        const _Float16* __restrict__ Wf,
        const float* __restrict__ bfc,
        float* __restrict__ out) {
    __shared__ char lds[2 * CHUNK_B];    // 40 KB double-buffered Wf fragment store

    const int lane = threadIdx.x & 63;
    const int wave = threadIdx.x >> 6;
    const int col  = lane & 15;          // MFMA: A-row m (sample) / B-col n / C-col
    const int quad = lane >> 4;          // MFMA: k-group / C row-group
    const int row_base = blockIdx.x * SAMPLES_PER_BLOCK + wave * 16;

    // accumulators: k per-t (2 halves), q SHARED across t (MFMA C-chain), yv per-t
    f32x4 acc_k[3][2];
    f32x4 acc_q[2];
    f32x4 acc_y[3];
    #pragma unroll
    for (int t = 0; t < 3; ++t) {
        acc_k[t][0] = (f32x4)0.f;
        acc_k[t][1] = (f32x4)0.f;
        acc_y[t]    = (f32x4)0.f;
    }
    acc_q[0] = (f32x4)0.f;
    acc_q[1] = (f32x4)0.f;

    // A-operand: lane (col,quad) -> sample row = col; K-permuted:
    //   x0 @ +quad*4 floats (k = 4q..4q+3), x1 @ +64B further (k = 16+4q..16+4q+3).
    // Each x-load instruction covers 16 full 64B lines, each line touched exactly once.
    const float* xbase = x + (size_t)(row_base + col) * (T_VIEWS * D_DIM) + quad * 4;
    const char*  wfg   = (const char*)Wf + lane * 16;   // per-lane global src for Wf staging

    f32x4 xA[2 * JPER];   // x regs, even chunks
    f32x4 xB[2 * JPER];   // x regs, odd chunks

    // stage Wf chunk u into lds[u&1] (4 waves x 5 glds of 1KB)
    auto GLDS = [&](int u) {
        #pragma unroll
        for (int i = 0; i < 5; ++i) {
            const int idx = wave * 5 + i;
            __builtin_amdgcn_global_load_lds(
                (const __attribute__((address_space(1))) void*)(wfg + (size_t)u * CHUNK_B + idx * 1024),
                (__attribute__((address_space(3))) void*)(lds + (u & 1) * CHUNK_B + idx * 1024),
                16, 0, 0);
        }
    };
    // issue the 8 x-loads of chunk u into xr (u compile-time after unroll) — PLAIN loads (v8)
    auto LOADX = [&](int u, f32x4* xr) {
        #pragma unroll
        for (int j = 0; j < JPER; ++j) {
            const int s = u * JPER + j, t = s >> 4, kc = s & 15;
            const float* xp = xbase + t * D_DIM + kc * 32;
            xr[2 * j]     = *(const f32x4*)xp;
            xr[2 * j + 1] = *(const f32x4*)(xp + 16);
        }
    };
    // compute chunk u from lds[u&1] + xr
    auto BODY = [&](int u, const f32x4* xr) {
        const char* buf = lds + (u & 1) * CHUNK_B;
        #pragma unroll
        for (int j = 0; j < JPER; ++j) {
            const int s = u * JPER + j, t = s >> 4;   // compile-time post-unroll
            h16x8 b[NT];
            #pragma unroll
            for (int n = 0; n < NT; ++n)
                b[n] = *(const h16x8*)(buf + j * STEP_B + n * 1024 + lane * 16);
            h16x8 a;
            #pragma unroll
            for (int i = 0; i < 4; ++i) {
                a[i]     = (_Float16)xr[2 * j][i];
                a[i + 4] = (_Float16)xr[2 * j + 1][i];
            }
            acc_k[t][0] = __builtin_amdgcn_mfma_f32_16x16x32_f16(a, b[0], acc_k[t][0], 0, 0, 0);
            acc_k[t][1] = __builtin_amdgcn_mfma_f32_16x16x32_f16(a, b[1], acc_k[t][1], 0, 0, 0);
            acc_q[0]    = __builtin_amdgcn_mfma_f32_16x16x32_f16(a, b[2], acc_q[0],    0, 0, 0);
            acc_q[1]    = __builtin_amdgcn_mfma_f32_16x16x32_f16(a, b[3], acc_q[1],    0, 0, 0);
            acc_y[t]    = __builtin_amdgcn_mfma_f32_16x16x32_f16(a, b[4], acc_y[t],    0, 0, 0);
        }
    };

    // ---- prologue: glds(0) + x(0) + x(1) in flight; retire only glds(0) (vmcnt 16 = x0+x1) ----
    GLDS(0);
    LOADX(0, xA);
    LOADX(1, xB);
    asm volatile("s_waitcnt vmcnt(16)" ::: "memory");
    __builtin_amdgcn_sched_barrier(0);
    __builtin_amdgcn_s_barrier();

    // ---- main loop, fully unrolled: counted vmcnt keeps x(u+2) in flight across barriers ----
    #pragma unroll
    for (int u = 0; u < NSUPER; ++u) {
        f32x4* xcur = (u & 1) ? xB : xA;
        if (u + 1 < NSUPER) GLDS(u + 1);          // into lds[(u+1)&1]
        BODY(u, xcur);                            // consume x(u); compiler auto-waits counted
        if (u + 2 < NSUPER) LOADX(u + 2, xcur);   // overwrite AFTER consumption (same parity)
        if (u + 1 < NSUPER) {
            if (u + 2 < NSUPER) {
                // queue (oldest->newest): x(u+1):8, glds(u+1):5, x(u+2):8 -> retire first 13
                asm volatile("s_waitcnt vmcnt(8)" ::: "memory");
            } else {
                // tail (u = NSUPER-2): nothing issued after glds(u+1) -> full drain is cheap
                asm volatile("s_waitcnt vmcnt(0)" ::: "memory");
            }
            __builtin_amdgcn_sched_barrier(0);
            __builtin_amdgcn_s_barrier();
        }
    }

    // ---------------- Epilogue (registers + shfl only) ----------------
    // C layout: element r holds sample row (quad*4 + r), column (n*16 + col).
    const float bias = (col < C_DIM) ? bfc[col] : 0.f;

    float outv[4];
    #pragma unroll
    for (int r = 0; r < 4; ++r) {
        const float qa = acc_q[0][r];     // q[sample][p=col]
        const float qb = acc_q[1][r];     // q[sample][p=16+col]
        float s0 = qa * acc_k[0][0][r] + qb * acc_k[0][1][r];
        float s1 = qa * acc_k[1][0][r] + qb * acc_k[1][1][r];
        float s2 = qa * acc_k[2][0][r] + qb * acc_k[2][1][r];
        #pragma unroll
        for (int msk = 1; msk <= 8; msk <<= 1) {
            s0 += __shfl_xor(s0, msk, 64);
            s1 += __shfl_xor(s1, msk, 64);
            s2 += __shfl_xor(s2, msk, 64);
        }
        const float mx = fmaxf(s0, fmaxf(s1, s2));
        const float e0 = __expf(s0 - mx);
        const float e1 = __expf(s1 - mx);
        const float e2 = __expf(s2 - mx);
        const float inv = 1.f / (e0 + e1 + e2);
        outv[r] = (e0 * acc_y[0][r] + e1 * acc_y[1][r] + e2 * acc_y[2][r]) * inv + bias;
    }
    if (col < C_DIM) {
        const int b0 = row_base + quad * 4;
        #pragma unroll
        for (int r = 0; r < 4; ++r)
            out[(size_t)(b0 + r) * C_DIM + col] = outv[r];
    }
}

extern "C" void kernel_launch(void* const* d_in, const int* in_sizes, int n_in,
                              void* d_out, int out_size, void* d_ws, size_t ws_size,
                              hipStream_t stream) {
    const float* x   = (const float*)d_in[0];
    const float* Wk  = (const float*)d_in[1];
    const float* Wv  = (const float*)d_in[2];
    const float* Wq  = (const float*)d_in[3];
    const float* Wfc = (const float*)d_in[4];
    const float* bfc = (const float*)d_in[5];
    _Float16* Wf = (_Float16*)d_ws;       // 3*80*512 halfs = 240 KB, fragment-ordered

    hipLaunchKernelGGL(build_weights, dim3(T_VIEWS * NROWS), dim3(D_DIM), 0, stream,
                       Wk, Wv, Wq, Wfc, Wf);

    const int B_TOTAL = in_sizes[0] / (T_VIEWS * D_DIM);      // 65536
    const int blocks = B_TOTAL / SAMPLES_PER_BLOCK;           // 1024
    hipLaunchKernelGGL(attn_fused, dim3(blocks), dim3(256), 0, stream,
                       x, Wf, bfc, (float*)d_out);
}

// Round 7
// 525.284 us; speedup vs baseline: 1.1656x; 1.0160x over previous
//
#include <hip/hip_runtime.h>

// Attention_884763263569 on gfx950 — v9 = v6 verbatim (FINAL; best measured: 524.06 us).
// x:[65536,3,512] f32, Wk/Wv:[32,512], Wq:[32,1536], Wfc:[10,32], bfc:[10] -> out [65536,10] f32.
//
// Session ledger (v7 double-launch diagnostic): total 524 us = ~436 us fixed harness
// (247 us poison fill @81% HBM peak + ~190 us restore parade) + ~88 us attn_fused
// + ~2 us build_weights. attn_fused floor = 64 us (403 MB x @ 6.3 TB/s) -> 73% of
// achievable; residual ~24 us is the DRAM-scheduling tax of 16 streams at 6 KB stride.
// A/B results: occupancy 2x (v3) null; Wf-LDS dbuf (v4) -28; contiguous-glds x staging
// (v5) null (occupancy cliff); full-unroll + counted-vmcnt pipeline (v6) -9; plain vs
// nontemporal x loads (v8) +10 (nt wins). This file restores the v6 optimum.
//
// Structure: folding out = sum_t a_t * (Wfc@Wv @ x_t) + bfc -> Wvf = Wfc@Wv [10,512].
// Per-t logical weight rows (80, fp16): 0..31 Wk | 32..63 Wq slice t | 64..73 Wvf | 74..79 zero,
// stored in MFMA-fragment order, K-permuted so both per-step x loads cover 16 full 64B lines.
// Main loop: 12 fully-unrolled super-chunks; Wf via global_load_lds double-buffer;
// x register-prefetch 2 chunks ahead; counted s_waitcnt vmcnt(8) + raw s_barrier between
// chunks (loads stay in flight across barriers); softmax+FC epilogue in registers/shfl.

typedef __attribute__((ext_vector_type(4))) float  f32x4;
typedef __attribute__((ext_vector_type(8))) _Float16 h16x8;

#define T_VIEWS 3
#define D_DIM   512
#define P_DIM   32
#define C_DIM   10
#define NROWS   80          // padded logical rows per t
#define NT      5           // n-tiles of 16
#define KC      16          // k-chunks of 32 per t
#define NSTEPS  48          // T_VIEWS*KC
#define JPER    4           // k-steps per super-chunk
#define NSUPER  (NSTEPS/JPER)            // 12
#define STEP_B  (NT*1024)                // 5120 B of fragments per k-step
#define CHUNK_B (JPER*STEP_B)            // 20480 B per super-chunk
#define WAVES_PER_BLOCK 4
#define SAMPLES_PER_BLOCK (16 * WAVES_PER_BLOCK)   // 64

// ---------------- Kernel A: build fragment-ordered fp16 weights in d_ws ----------------
// Logical (t, j, d) -> frag addr (((t*KC+kc)*NT+n)*64 + quad*16+col)*8 + jj
// K-permutation within a 32-chunk: r = d&31 -> quad=(r>>2)&3, jj=((r>>4)<<2)|(r&3),
// i.e. element jj of quad q is k = (jj<4 ? 4q+jj : 16+4q+jj-4). Matches the A-side loads.
__global__ void build_weights(const float* __restrict__ Wk,
                              const float* __restrict__ Wv,
                              const float* __restrict__ Wq,
                              const float* __restrict__ Wfc,
                              _Float16* __restrict__ Wf) {
    const int row = blockIdx.x;          // 0 .. 3*80-1
    const int t   = row / NROWS;
    const int j   = row % NROWS;
    const int d   = threadIdx.x;         // 0..511
    float val;
    if (j < 32) {
        val = Wk[j * D_DIM + d];
    } else if (j < 64) {
        const int p = j - 32;
        val = Wq[p * (T_VIEWS * D_DIM) + t * D_DIM + d];
    } else if (j < 64 + C_DIM) {
        const int i = j - 64;
        float s = 0.f;
        #pragma unroll
        for (int p = 0; p < P_DIM; ++p)
            s += Wfc[i * P_DIM + p] * Wv[p * D_DIM + d];
        val = s;
    } else {
        val = 0.f;                        // pad rows (d_ws is poisoned -> must zero)
    }
    const int n = j >> 4, coln = j & 15;
    const int kc = d >> 5, r = d & 31;
    const int quad = (r >> 2) & 3;                 // K-permuted quad
    const int jj   = ((r >> 4) << 2) | (r & 3);    // K-permuted element index
    const size_t addr = (size_t)((((t * KC + kc) * NT + n) * 64) + quad * 16 + coln) * 8 + jj;
    Wf[addr] = (_Float16)val;
}

// ---------------- Main fused kernel ----------------
__global__ __launch_bounds__(256, 3) void attn_fused(
        const float* __restrict__ x,
        const _Float16* __restrict__ Wf,
        const float* __restrict__ bfc,
        float* __restrict__ out) {
    __shared__ char lds[2 * CHUNK_B];    // 40 KB double-buffered Wf fragment store

    const int lane = threadIdx.x & 63;
    const int wave = threadIdx.x >> 6;
    const int col  = lane & 15;          // MFMA: A-row m (sample) / B-col n / C-col
    const int quad = lane >> 4;          // MFMA: k-group / C row-group
    const int row_base = blockIdx.x * SAMPLES_PER_BLOCK + wave * 16;

    // accumulators: k per-t (2 halves), q SHARED across t (MFMA C-chain), yv per-t
    f32x4 acc_k[3][2];
    f32x4 acc_q[2];
    f32x4 acc_y[3];
    #pragma unroll
    for (int t = 0; t < 3; ++t) {
        acc_k[t][0] = (f32x4)0.f;
        acc_k[t][1] = (f32x4)0.f;
        acc_y[t]    = (f32x4)0.f;
    }
    acc_q[0] = (f32x4)0.f;
    acc_q[1] = (f32x4)0.f;

    // A-operand: lane (col,quad) -> sample row = col; K-permuted:
    //   x0 @ +quad*4 floats (k = 4q..4q+3), x1 @ +64B further (k = 16+4q..16+4q+3).
    // Each x-load instruction covers 16 full 64B lines, each line touched exactly once.
    const float* xbase = x + (size_t)(row_base + col) * (T_VIEWS * D_DIM) + quad * 4;
    const char*  wfg   = (const char*)Wf + lane * 16;   // per-lane global src for Wf staging

    f32x4 xA[2 * JPER];   // x regs, even chunks
    f32x4 xB[2 * JPER];   // x regs, odd chunks

    // stage Wf chunk u into lds[u&1] (4 waves x 5 glds of 1KB)
    auto GLDS = [&](int u) {
        #pragma unroll
        for (int i = 0; i < 5; ++i) {
            const int idx = wave * 5 + i;
            __builtin_amdgcn_global_load_lds(
                (const __attribute__((address_space(1))) void*)(wfg + (size_t)u * CHUNK_B + idx * 1024),
                (__attribute__((address_space(3))) void*)(lds + (u & 1) * CHUNK_B + idx * 1024),
                16, 0, 0);
        }
    };
    // issue the 8 x-loads of chunk u into xr (u compile-time after unroll)
    auto LOADX = [&](int u, f32x4* xr) {
        #pragma unroll
        for (int j = 0; j < JPER; ++j) {
            const int s = u * JPER + j, t = s >> 4, kc = s & 15;
            const float* xp = xbase + t * D_DIM + kc * 32;
            xr[2 * j]     = __builtin_nontemporal_load((const f32x4*)xp);
            xr[2 * j + 1] = __builtin_nontemporal_load((const f32x4*)(xp + 16));
        }
    };
    // compute chunk u from lds[u&1] + xr
    auto BODY = [&](int u, const f32x4* xr) {
        const char* buf = lds + (u & 1) * CHUNK_B;
        #pragma unroll
        for (int j = 0; j < JPER; ++j) {
            const int s = u * JPER + j, t = s >> 4;   // compile-time post-unroll
            h16x8 b[NT];
            #pragma unroll
            for (int n = 0; n < NT; ++n)
                b[n] = *(const h16x8*)(buf + j * STEP_B + n * 1024 + lane * 16);
            h16x8 a;
            #pragma unroll
            for (int i = 0; i < 4; ++i) {
                a[i]     = (_Float16)xr[2 * j][i];
                a[i + 4] = (_Float16)xr[2 * j + 1][i];
            }
            acc_k[t][0] = __builtin_amdgcn_mfma_f32_16x16x32_f16(a, b[0], acc_k[t][0], 0, 0, 0);
            acc_k[t][1] = __builtin_amdgcn_mfma_f32_16x16x32_f16(a, b[1], acc_k[t][1], 0, 0, 0);
            acc_q[0]    = __builtin_amdgcn_mfma_f32_16x16x32_f16(a, b[2], acc_q[0],    0, 0, 0);
            acc_q[1]    = __builtin_amdgcn_mfma_f32_16x16x32_f16(a, b[3], acc_q[1],    0, 0, 0);
            acc_y[t]    = __builtin_amdgcn_mfma_f32_16x16x32_f16(a, b[4], acc_y[t],    0, 0, 0);
        }
    };

    // ---- prologue: glds(0) + x(0) + x(1) in flight; retire only glds(0) (vmcnt 16 = x0+x1) ----
    GLDS(0);
    LOADX(0, xA);
    LOADX(1, xB);
    asm volatile("s_waitcnt vmcnt(16)" ::: "memory");
    __builtin_amdgcn_sched_barrier(0);
    __builtin_amdgcn_s_barrier();

    // ---- main loop, fully unrolled: counted vmcnt keeps x(u+2) in flight across barriers ----
    #pragma unroll
    for (int u = 0; u < NSUPER; ++u) {
        f32x4* xcur = (u & 1) ? xB : xA;
        if (u + 1 < NSUPER) GLDS(u + 1);          // into lds[(u+1)&1]
        BODY(u, xcur);                            // consume x(u); compiler auto-waits counted
        if (u + 2 < NSUPER) LOADX(u + 2, xcur);   // overwrite AFTER consumption (same parity)
        if (u + 1 < NSUPER) {
            if (u + 2 < NSUPER) {
                // queue (oldest->newest): x(u+1):8, glds(u+1):5, x(u+2):8 -> retire first 13
                asm volatile("s_waitcnt vmcnt(8)" ::: "memory");
            } else {
                // tail (u = NSUPER-2): nothing issued after glds(u+1) -> full drain is cheap
                asm volatile("s_waitcnt vmcnt(0)" ::: "memory");
            }
            __builtin_amdgcn_sched_barrier(0);
            __builtin_amdgcn_s_barrier();
        }
    }

    // ---------------- Epilogue (registers + shfl only) ----------------
    // C layout: element r holds sample row (quad*4 + r), column (n*16 + col).
    const float bias = (col < C_DIM) ? bfc[col] : 0.f;

    float outv[4];
    #pragma unroll
    for (int r = 0; r < 4; ++r) {
        const float qa = acc_q[0][r];     // q[sample][p=col]
        const float qb = acc_q[1][r];     // q[sample][p=16+col]
        float s0 = qa * acc_k[0][0][r] + qb * acc_k[0][1][r];
        float s1 = qa * acc_k[1][0][r] + qb * acc_k[1][1][r];
        float s2 = qa * acc_k[2][0][r] + qb * acc_k[2][1][r];
        #pragma unroll
        for (int msk = 1; msk <= 8; msk <<= 1) {
            s0 += __shfl_xor(s0, msk, 64);
            s1 += __shfl_xor(s1, msk, 64);
            s2 += __shfl_xor(s2, msk, 64);
        }
        const float mx = fmaxf(s0, fmaxf(s1, s2));
        const float e0 = __expf(s0 - mx);
        const float e1 = __expf(s1 - mx);
        const float e2 = __expf(s2 - mx);
        const float inv = 1.f / (e0 + e1 + e2);
        outv[r] = (e0 * acc_y[0][r] + e1 * acc_y[1][r] + e2 * acc_y[2][r]) * inv + bias;
    }
    if (col < C_DIM) {
        const int b0 = row_base + quad * 4;
        #pragma unroll
        for (int r = 0; r < 4; ++r)
            out[(size_t)(b0 + r) * C_DIM + col] = outv[r];
    }
}

extern "C" void kernel_launch(void* const* d_in, const int* in_sizes, int n_in,
                              void* d_out, int out_size, void* d_ws, size_t ws_size,
                              hipStream_t stream) {
    const float* x   = (const float*)d_in[0];
    const float* Wk  = (const float*)d_in[1];
    const float* Wv  = (const float*)d_in[2];
    const float* Wq  = (const float*)d_in[3];
    const float* Wfc = (const float*)d_in[4];
    const float* bfc = (const float*)d_in[5];
    _Float16* Wf = (_Float16*)d_ws;       // 3*80*512 halfs = 240 KB, fragment-ordered

    hipLaunchKernelGGL(build_weights, dim3(T_VIEWS * NROWS), dim3(D_DIM), 0, stream,
                       Wk, Wv, Wq, Wfc, Wf);

    const int B_TOTAL = in_sizes[0] / (T_VIEWS * D_DIM);      // 65536
    const int blocks = B_TOTAL / SAMPLES_PER_BLOCK;           // 1024
    hipLaunchKernelGGL(attn_fused, dim3(blocks), dim3(256), 0, stream,
                       x, Wf, bfc, (float*)d_out);
}